// Round 4
// baseline (150.585 us; speedup 1.0000x reference)
//
#include <hip/hip_runtime.h>

#define PRIME1 2654435761u
#define PRIME2 805459861u
#define PRIME3 3674653429u

typedef float f2v __attribute__((ext_vector_type(2)));
typedef float f4v __attribute__((ext_vector_type(4)));

// Level-major mapping: each block = 256 points x ONE level; (blockIdx % 8)
// == (level % 8) so each XCD's L2 holds a single ~4MB level table.
// Corner-pair gathers: corners paired by bit0 share a 64B line when the
// dim-0 XOR delta e0==1 (u0 even) or always for under-hash levels ->
// one dwordx4 fetches both corners; only odd-u0 lanes on fast levels issue
// the partner dwordx2 (exec-masked). Cuts gather requests to ~70%.
template <bool DIRECT>
__global__ __launch_bounds__(256) void hash_enc_kernel(
    const float* __restrict__ xyzts,        // [npts,4]
    const float* __restrict__ table,        // [total]
    const int* __restrict__ shapes,         // [16,4]
    const unsigned int* __restrict__ sizes, // [16]
    const int* __restrict__ indicator,      // [16]
    const int* __restrict__ offsets,        // [16]
    float* __restrict__ dst,                // ws [16,npts,2] or out [npts,32]
    int npts, int nchunks)
{
    int b = blockIdx.x;
    int half = b / (nchunks * 8);             // 0 -> levels 0..7, 1 -> 8..15
    int within = b % (nchunks * 8);
    int level = (within & 7) + (half << 3);   // uniform in the block
    int chunk = within >> 3;
    int n = chunk * 256 + (int)threadIdx.x;
    if (n >= npts) return;

    // level is wave-uniform -> scalar loads
    int4 rs = reinterpret_cast<const int4*>(shapes)[level];
    unsigned int size = sizes[level];
    unsigned int msk = size - 1u;       // indicator==0 => size == 2^19 (pow2)
    bool ind = (indicator[level] != 0); // wave-uniform
    int off = offsets[level];

    float4 x = reinterpret_cast<const float4*>(xyzts)[n];

    float r0 = (float)rs.x, r1 = (float)rs.y, r2 = (float)rs.z, r3 = (float)rs.w;
    float p0 = x.x * r0, p1 = x.y * r1, p2 = x.z * r2, p3 = x.w * r3;
    float g0 = fminf(fmaxf(floorf(p0), 0.f), r0 - 1.f);
    float g1 = fminf(fmaxf(floorf(p1), 0.f), r1 - 1.f);
    float g2 = fminf(fmaxf(floorf(p2), 0.f), r2 - 1.f);
    float g3 = fminf(fmaxf(floorf(p3), 0.f), r3 - 1.f);
    float f0 = fminf(fmaxf(p0 - g0, 0.f), 1.f);
    float f1 = fminf(fmaxf(p1 - g1, 0.f), 1.f);
    float f2 = fminf(fmaxf(p2 - g2, 0.f), 1.f);
    float f3 = fminf(fmaxf(p3 - g3, 0.f), 1.f);
    unsigned int u0 = (unsigned int)g0, u1 = (unsigned int)g1;
    unsigned int u2 = (unsigned int)g2, u3 = (unsigned int)g3;

    unsigned int s1 = (unsigned int)(rs.x + 1);
    unsigned int s2 = s1 * (unsigned int)(rs.y + 1);
    unsigned int s3 = s2 * (unsigned int)(rs.z + 1);

    // fast-hash base (even corner in dim0) + per-dim XOR deltas
    unsigned int a1 = u1 * PRIME1, a2 = u2 * PRIME2, a3 = u3 * PRIME3;
    unsigned int xb = u0 ^ a1 ^ a2 ^ a3;
    unsigned int e0 = u0 ^ (u0 + 1u);        // ==1 iff u0 even
    unsigned int e1 = a1 ^ ((u1 + 1u) * PRIME1);
    unsigned int e2 = a2 ^ ((u2 + 1u) * PRIME2);
    unsigned int e3 = a3 ^ ((u3 + 1u) * PRIME3);

    // under-hash base; under < raw <= size when ind==1 -> no mod needed
    unsigned int ab = u0 + u1 * s1 + u2 * s2 + u3 * s3;

    float om0 = 1.f - f0, om1 = 1.f - f1, om2 = 1.f - f2, om3 = 1.f - f3;

    const float* tb = table + off;
    bool need_partner = (!ind) && (e0 != 1u);   // per-lane, loop-invariant

    float acc0 = 0.f, acc1 = 0.f;
#pragma unroll
    for (int cp = 0; cp < 8; ++cp) {           // pair cp covers corners 2cp,2cp+1
        unsigned int hfe = xb, hue = ab;
        if (cp & 1) { hfe ^= e1; hue += s1; }
        if (cp & 2) { hfe ^= e2; hue += s2; }
        if (cp & 4) { hfe ^= e3; hue += s3; }
        unsigned int he = ind ? hue : (hfe & msk);       // even-corner entry
        unsigned int base = ind ? he : (he & ~1u);       // x4 covers {base,base+1}
        f4v v4 = *reinterpret_cast<const f4v*>(tb + 2u * base);

        // ind: (v4.xy, v4.zw) = (he, he+1) = (even, odd) corner directly.
        // fast: entries (he&~1, he|1); pick halves by he&1. When e0==1 the
        // other half IS the odd corner; otherwise it's overwritten below.
        bool swp = (!ind) && (he & 1u);
        float vex = swp ? v4.z : v4.x;
        float vey = swp ? v4.w : v4.y;
        float vox = swp ? v4.x : v4.z;
        float voy = swp ? v4.y : v4.w;
        if (need_partner) {                    // ~50% lanes on fast levels
            unsigned int ho = (hfe ^ e0) & msk;
            f2v p = *reinterpret_cast<const f2v*>(tb + 2u * ho);
            vox = p.x; voy = p.y;
        }

        float rest = ((cp & 1) ? f1 : om1);
        rest *= ((cp & 2) ? f2 : om2);
        rest *= ((cp & 4) ? f3 : om3);
        float we = om0 * rest, wo = f0 * rest;
        acc0 += we * vex; acc0 += wo * vox;
        acc1 += we * vey; acc1 += wo * voy;
    }

    f2v res;
    res.x = acc0; res.y = acc1;
    if (DIRECT) {
        reinterpret_cast<f2v*>(dst)[(size_t)n * 16 + level] = res;
    } else {
        // coalesced full-line streaming store; keep it out of L2 (table owns L2)
        __builtin_nontemporal_store(
            res, reinterpret_cast<f2v*>(dst) + (size_t)level * npts + n);
    }
}

// ws [16][npts] float2  ->  out [npts][32] float. Reads coalesced per level,
// writes 128B contiguous per lane (lines fully covered -> full-line writeback).
__global__ __launch_bounds__(256) void transpose_kernel(
    const float* __restrict__ ws, float* __restrict__ out, int npts)
{
    int n = blockIdx.x * 256 + (int)threadIdx.x;
    if (n >= npts) return;
    const f2v* w = reinterpret_cast<const f2v*>(ws);
    f2v v[16];
#pragma unroll
    for (int l = 0; l < 16; ++l)
        v[l] = w[(size_t)l * npts + n];
    f4v* o = reinterpret_cast<f4v*>(out + (size_t)n * 32);
#pragma unroll
    for (int j = 0; j < 8; ++j) {
        f4v q;
        q.x = v[2 * j].x; q.y = v[2 * j].y;
        q.z = v[2 * j + 1].x; q.w = v[2 * j + 1].y;
        __builtin_nontemporal_store(q, o + j);
    }
}

extern "C" void kernel_launch(void* const* d_in, const int* in_sizes, int n_in,
                              void* d_out, int out_size, void* d_ws, size_t ws_size,
                              hipStream_t stream) {
    const float* xyzts = (const float*)d_in[0];
    const float* table = (const float*)d_in[1];
    const int* shapes = (const int*)d_in[2];
    const unsigned int* sizes = (const unsigned int*)d_in[3];
    const int* indicator = (const int*)d_in[4];
    const int* offsets = (const int*)d_in[5];
    float* out = (float*)d_out;

    int npts = in_sizes[0] / 4;
    int nchunks = (npts + 255) / 256;
    int blocks = nchunks * 16;

    size_t ws_needed = (size_t)npts * 16 * 2 * sizeof(float);
    if (ws_size >= ws_needed) {
        float* ws = (float*)d_ws;
        hash_enc_kernel<false><<<blocks, 256, 0, stream>>>(
            xyzts, table, shapes, sizes, indicator, offsets, ws, npts, nchunks);
        transpose_kernel<<<nchunks, 256, 0, stream>>>(ws, out, npts);
    } else {
        hash_enc_kernel<true><<<blocks, 256, 0, stream>>>(
            xyzts, table, shapes, sizes, indicator, offsets, out, npts, nchunks);
    }
}

// Round 6
// 131.195 us; speedup vs baseline: 1.1478x; 1.1478x over previous
//
#include <hip/hip_runtime.h>

#define PRIME1 2654435761u
#define PRIME2 805459861u
#define PRIME3 3674653429u

typedef float f2v __attribute__((ext_vector_type(2)));
typedef float f4v __attribute__((ext_vector_type(4)));

// Level-major mapping: each block = 256 points x ONE level; (blockIdx % 8)
// == (level % 8) so each XCD's L2 holds a single ~4MB level table.
// Inner structure: 3 phases -- (1) compute all 16 corner indices,
// (2) issue all 16 independent 8B gathers into registers (max MLP),
// (3) weighted accumulate. Round-4 corner-pairing reverted: adjacent-in-
// program-order same-line corners already hit L1; pairing only added
// misaligned x4 splits and masked-load overhead.
template <bool DIRECT>
__global__ __launch_bounds__(256) void hash_enc_kernel(
    const float* __restrict__ xyzts,        // [npts,4]
    const float* __restrict__ table,        // [total]
    const int* __restrict__ shapes,         // [16,4]
    const unsigned int* __restrict__ sizes, // [16]
    const int* __restrict__ indicator,      // [16]
    const int* __restrict__ offsets,        // [16]
    float* __restrict__ dst,                // ws [16,npts,2] or out [npts,32]
    int npts, int nchunks)
{
    int b = blockIdx.x;
    int half = b / (nchunks * 8);             // 0 -> levels 0..7, 1 -> 8..15
    int within = b % (nchunks * 8);
    int level = (within & 7) + (half << 3);   // uniform in the block
    int chunk = within >> 3;
    int n = chunk * 256 + (int)threadIdx.x;
    if (n >= npts) return;

    // level is wave-uniform -> scalar loads
    int4 rs = reinterpret_cast<const int4*>(shapes)[level];
    unsigned int size = sizes[level];
    unsigned int msk = size - 1u;       // indicator==0 => size == 2^19 (pow2)
    bool ind = (indicator[level] != 0);
    int off = offsets[level];

    // NT point load: don't let the 2MB/level xyzts stream evict table lines
    f4v x = __builtin_nontemporal_load(
        reinterpret_cast<const f4v*>(xyzts) + n);

    float r0 = (float)rs.x, r1 = (float)rs.y, r2 = (float)rs.z, r3 = (float)rs.w;
    float p0 = x.x * r0, p1 = x.y * r1, p2 = x.z * r2, p3 = x.w * r3;
    float g0 = fminf(fmaxf(floorf(p0), 0.f), r0 - 1.f);
    float g1 = fminf(fmaxf(floorf(p1), 0.f), r1 - 1.f);
    float g2 = fminf(fmaxf(floorf(p2), 0.f), r2 - 1.f);
    float g3 = fminf(fmaxf(floorf(p3), 0.f), r3 - 1.f);
    float f0 = fminf(fmaxf(p0 - g0, 0.f), 1.f);
    float f1 = fminf(fmaxf(p1 - g1, 0.f), 1.f);
    float f2 = fminf(fmaxf(p2 - g2, 0.f), 1.f);
    float f3 = fminf(fmaxf(p3 - g3, 0.f), 1.f);
    unsigned int u0 = (unsigned int)g0, u1 = (unsigned int)g1;
    unsigned int u2 = (unsigned int)g2, u3 = (unsigned int)g3;

    unsigned int s1 = (unsigned int)(rs.x + 1);
    unsigned int s2 = s1 * (unsigned int)(rs.y + 1);
    unsigned int s3 = s2 * (unsigned int)(rs.z + 1);

    unsigned int a1 = u1 * PRIME1, a2 = u2 * PRIME2, a3 = u3 * PRIME3;
    unsigned int xb = u0 ^ a1 ^ a2 ^ a3;
    unsigned int e0 = u0 ^ (u0 + 1u);
    unsigned int e1 = a1 ^ ((u1 + 1u) * PRIME1);
    unsigned int e2 = a2 ^ ((u2 + 1u) * PRIME2);
    unsigned int e3 = a3 ^ ((u3 + 1u) * PRIME3);

    unsigned int ab = u0 + u1 * s1 + u2 * s2 + u3 * s3;

    float om0 = 1.f - f0, om1 = 1.f - f1, om2 = 1.f - f2, om3 = 1.f - f3;

    const float* tb = table + off;

    // Phase 1: all 16 corner indices (static unroll -> registers)
    unsigned int idx[16];
#pragma unroll
    for (int c = 0; c < 16; ++c) {
        unsigned int hf = xb, hu = ab;
        if (c & 1) { hf ^= e0; hu += 1u; }
        if (c & 2) { hf ^= e1; hu += s1; }
        if (c & 4) { hf ^= e2; hu += s2; }
        if (c & 8) { hf ^= e3; hu += s3; }
        idx[c] = ind ? hu : (hf & msk);
    }

    // Phase 2: issue all 16 independent gathers (16 outstanding per wave)
    f2v v[16];
#pragma unroll
    for (int c = 0; c < 16; ++c)
        v[c] = *reinterpret_cast<const f2v*>(tb + 2u * idx[c]);

    // Phase 3: weighted accumulate
    float acc0 = 0.f, acc1 = 0.f;
#pragma unroll
    for (int c = 0; c < 16; ++c) {
        float w = (c & 1) ? f0 : om0;
        w *= (c & 2) ? f1 : om1;
        w *= (c & 4) ? f2 : om2;
        w *= (c & 8) ? f3 : om3;
        acc0 += w * v[c].x;
        acc1 += w * v[c].y;
    }

    f2v res;
    res.x = acc0; res.y = acc1;
    if (DIRECT) {
        reinterpret_cast<f2v*>(dst)[(size_t)n * 16 + level] = res;
    } else {
        // coalesced full-line streaming store; keep it out of L2 (table owns L2)
        __builtin_nontemporal_store(
            res, reinterpret_cast<f2v*>(dst) + (size_t)level * npts + n);
    }
}

// ws [16][npts] float2  ->  out [npts][32] float. Reads coalesced per level,
// writes 128B contiguous per lane (lines fully covered -> full-line writeback).
__global__ __launch_bounds__(256) void transpose_kernel(
    const float* __restrict__ ws, float* __restrict__ out, int npts)
{
    int n = blockIdx.x * 256 + (int)threadIdx.x;
    if (n >= npts) return;
    const f2v* w = reinterpret_cast<const f2v*>(ws);
    f2v v[16];
#pragma unroll
    for (int l = 0; l < 16; ++l)
        v[l] = w[(size_t)l * npts + n];
    f4v* o = reinterpret_cast<f4v*>(out + (size_t)n * 32);
#pragma unroll
    for (int j = 0; j < 8; ++j) {
        f4v q;
        q.x = v[2 * j].x; q.y = v[2 * j].y;
        q.z = v[2 * j + 1].x; q.w = v[2 * j + 1].y;
        __builtin_nontemporal_store(q, o + j);
    }
}

extern "C" void kernel_launch(void* const* d_in, const int* in_sizes, int n_in,
                              void* d_out, int out_size, void* d_ws, size_t ws_size,
                              hipStream_t stream) {
    const float* xyzts = (const float*)d_in[0];
    const float* table = (const float*)d_in[1];
    const int* shapes = (const int*)d_in[2];
    const unsigned int* sizes = (const unsigned int*)d_in[3];
    const int* indicator = (const int*)d_in[4];
    const int* offsets = (const int*)d_in[5];
    float* out = (float*)d_out;

    int npts = in_sizes[0] / 4;
    int nchunks = (npts + 255) / 256;
    int blocks = nchunks * 16;

    size_t ws_needed = (size_t)npts * 16 * 2 * sizeof(float);
    if (ws_size >= ws_needed) {
        float* ws = (float*)d_ws;
        hash_enc_kernel<false><<<blocks, 256, 0, stream>>>(
            xyzts, table, shapes, sizes, indicator, offsets, ws, npts, nchunks);
        transpose_kernel<<<nchunks, 256, 0, stream>>>(ws, out, npts);
    } else {
        hash_enc_kernel<true><<<blocks, 256, 0, stream>>>(
            xyzts, table, shapes, sizes, indicator, offsets, out, npts, nchunks);
    }
}